// Round 5
// baseline (481.607 us; speedup 1.0000x reference)
//
#include <hip/hip_runtime.h>

#define N_NODES_C 100000
#define N_EDGES_C 800000
#define FEATS 100
#define NCLS 50
#define GENE 20000
#define SCAN_BLK 1024
#define SCAN_NBLK ((N_NODES_C + SCAN_BLK - 1) / SCAN_BLK)   // 98

// ---------------------------------------------------------------------------
// Degree count (int atomics)
// ---------------------------------------------------------------------------
__global__ void deg_count_kernel(const int* __restrict__ dst,
                                 int* __restrict__ deg) {
    int e = blockIdx.x * blockDim.x + threadIdx.x;
    if (e >= N_EDGES_C) return;
    atomicAdd(&deg[dst[e]], 1);
}

// ---------------------------------------------------------------------------
// 3-kernel exclusive scan over deg[100000] -> row_ptr[100001]
// ---------------------------------------------------------------------------
__global__ __launch_bounds__(1024) void scan1_kernel(int* __restrict__ deg,
                                                     int* __restrict__ bsum) {
    __shared__ int wsum[16];
    const int i = blockIdx.x * SCAN_BLK + threadIdx.x;
    const int lane = threadIdx.x & 63;
    const int wid = threadIdx.x >> 6;
    int v = (i < N_NODES_C) ? deg[i] : 0;
    #pragma unroll
    for (int d = 1; d < 64; d <<= 1) {
        int t = __shfl_up(v, d);
        if (lane >= d) v += t;
    }
    if (lane == 63) wsum[wid] = v;
    __syncthreads();
    if (wid == 0) {
        int s = (lane < 16) ? wsum[lane] : 0;
        #pragma unroll
        for (int d = 1; d < 16; d <<= 1) {
            int t = __shfl_up(s, d);
            if (lane >= d) s += t;
        }
        if (lane < 16) wsum[lane] = s;
    }
    __syncthreads();
    if (wid > 0) v += wsum[wid - 1];
    if (i < N_NODES_C) deg[i] = v;
    if (threadIdx.x == SCAN_BLK - 1) bsum[blockIdx.x] = v;
}

__global__ void scan2_kernel(int* __restrict__ bsum) {
    __shared__ int tmp[SCAN_NBLK];
    if (threadIdx.x < SCAN_NBLK) tmp[threadIdx.x] = bsum[threadIdx.x];
    __syncthreads();
    if (threadIdx.x == 0) {
        int off = 0;
        for (int j = 0; j < SCAN_NBLK; ++j) { int t = tmp[j]; tmp[j] = off; off += t; }
    }
    __syncthreads();
    if (threadIdx.x < SCAN_NBLK) bsum[threadIdx.x] = tmp[threadIdx.x];
}

__global__ __launch_bounds__(1024) void scan3_kernel(const int* __restrict__ incl,
                                                     const int* __restrict__ boff,
                                                     int* __restrict__ rp,
                                                     int* __restrict__ cursor) {
    int i = blockIdx.x * SCAN_BLK + threadIdx.x;
    if (i >= N_NODES_C) return;
    int v = incl[i] + boff[blockIdx.x];
    rp[i + 1] = v;
    cursor[i + 1] = v;
    if (i == 0) { rp[0] = 0; cursor[0] = 0; }
}

// ---------------------------------------------------------------------------
// CSR fill: per edge compute scale inline, append (src, scale) to dst bucket
// ---------------------------------------------------------------------------
__global__ void csr_fill_kernel(const int* __restrict__ node_ids,
                                const int* __restrict__ src,
                                const int* __restrict__ dst,
                                const float* __restrict__ ew,
                                const float* __restrict__ alpha,
                                int* __restrict__ cursor,
                                int2* __restrict__ csr) {
    int e = blockIdx.x * blockDim.x + threadIdx.x;
    if (e >= N_EDGES_C) return;
    int s = src[e];
    int d = dst[e];
    int sid = node_ids[s];
    int did = node_ids[d];
    int idx = GENE + 1;                        // cell-cell
    if (sid >= 0 && did < 0) idx = sid;        // gene -> cell
    else if (did >= 0 && sid < 0) idx = did;   // cell -> gene
    else if (sid >= 0 && did >= 0) idx = GENE; // gene -> gene
    float sc = alpha[idx] * ew[e];
    int pos = atomicAdd(&cursor[d], 1);
    csr[pos] = make_int2(s, __float_as_int(sc));
}

// ---------------------------------------------------------------------------
// Aggregation v3: 2 nodes per wave (32 lanes each, float4 x 25 slots),
// clamped x4 unroll -> always 4 row loads in flight, no serial tail.
// ---------------------------------------------------------------------------
__global__ __launch_bounds__(256) void aggregate_kernel(
        const float* __restrict__ hin,
        const int* __restrict__ rp,
        const int2* __restrict__ csr,
        float* __restrict__ neigh) {
    const int node = (blockIdx.x * 256 + threadIdx.x) >> 5;
    const int lane = threadIdx.x & 31;
    const int ll = (lane < FEATS / 4) ? lane : (FEATS / 4 - 1);  // clamp
    if (node >= N_NODES_C) return;
    const int beg = rp[node];
    const int end = rp[node + 1];
    float a0 = 0.0f, a1 = 0.0f, a2 = 0.0f, a3 = 0.0f;
    for (int k = beg; k < end; k += 4) {
        const int k1 = min(k + 1, end - 1);
        const int k2 = min(k + 2, end - 1);
        const int k3 = min(k + 3, end - 1);
        int2 e0 = csr[k];
        int2 e1 = csr[k1];
        int2 e2 = csr[k2];
        int2 e3 = csr[k3];
        float4 x0 = ((const float4*)(hin + (size_t)e0.x * FEATS))[ll];
        float4 x1 = ((const float4*)(hin + (size_t)e1.x * FEATS))[ll];
        float4 x2 = ((const float4*)(hin + (size_t)e2.x * FEATS))[ll];
        float4 x3 = ((const float4*)(hin + (size_t)e3.x * FEATS))[ll];
        float w0 = __int_as_float(e0.y);
        float w1 = (k + 1 < end) ? __int_as_float(e1.y) : 0.0f;
        float w2 = (k + 2 < end) ? __int_as_float(e2.y) : 0.0f;
        float w3 = (k + 3 < end) ? __int_as_float(e3.y) : 0.0f;
        a0 = fmaf(x0.x, w0, a0); a1 = fmaf(x0.y, w0, a1);
        a2 = fmaf(x0.z, w0, a2); a3 = fmaf(x0.w, w0, a3);
        a0 = fmaf(x1.x, w1, a0); a1 = fmaf(x1.y, w1, a1);
        a2 = fmaf(x1.z, w1, a2); a3 = fmaf(x1.w, w1, a3);
        a0 = fmaf(x2.x, w2, a0); a1 = fmaf(x2.y, w2, a1);
        a2 = fmaf(x2.z, w2, a2); a3 = fmaf(x2.w, w2, a3);
        a0 = fmaf(x3.x, w3, a0); a1 = fmaf(x3.y, w3, a1);
        a2 = fmaf(x3.z, w3, a2); a3 = fmaf(x3.w, w3, a3);
    }
    const float invd = (end > beg) ? 1.0f / (float)(end - beg) : 0.0f;
    if (lane < FEATS / 4) {
        ((float4*)(neigh + (size_t)node * FEATS))[lane] =
            make_float4(a0 * invd, a1 * invd, a2 * invd, a3 * invd);
    }
}

// ---------------------------------------------------------------------------
// Dense (layer 1): one 32-row tile per block (grid = N/32). 256 threads.
// 2 groups x 16 rows, j = tid&127 (<100 active). W row in VGPRs.
// ---------------------------------------------------------------------------
__global__ __launch_bounds__(256) void dense32_kernel(
        const float* __restrict__ in,
        const float* __restrict__ W,
        const float* __restrict__ b,
        float* __restrict__ out) {
    __shared__ float rows[32][FEATS];
    const int tid = threadIdx.x;
    const int n0 = blockIdx.x * 32;
    const int j = tid & 127;
    const int grp = tid >> 7;

    for (int i = tid; i < 32 * (FEATS / 4); i += 256) {
        int r = i / (FEATS / 4);
        int k4 = i - r * (FEATS / 4);
        float4 v = reinterpret_cast<const float4*>(in + (size_t)(n0 + r) * FEATS)[k4];
        *reinterpret_cast<float4*>(&rows[r][k4 * 4]) = v;
    }

    float w[FEATS];
    float bias = 0.0f;
    if (j < FEATS) {
        bias = b[j];
        #pragma unroll
        for (int k4 = 0; k4 < FEATS / 4; ++k4) {
            float4 v = reinterpret_cast<const float4*>(W + (size_t)j * FEATS)[k4];
            w[4 * k4 + 0] = v.x;
            w[4 * k4 + 1] = v.y;
            w[4 * k4 + 2] = v.z;
            w[4 * k4 + 3] = v.w;
        }
    }
    __syncthreads();

    if (j < FEATS) {
        float acc[16];
        #pragma unroll
        for (int r = 0; r < 16; ++r) acc[r] = bias;
        #pragma unroll
        for (int k4 = 0; k4 < FEATS / 4; ++k4) {
            const float wx = w[4 * k4 + 0];
            const float wy = w[4 * k4 + 1];
            const float wz = w[4 * k4 + 2];
            const float ww = w[4 * k4 + 3];
            #pragma unroll
            for (int r = 0; r < 16; ++r) {
                float4 hv = *reinterpret_cast<const float4*>(&rows[grp * 16 + r][4 * k4]);
                acc[r] = fmaf(hv.x, wx, acc[r]);
                acc[r] = fmaf(hv.y, wy, acc[r]);
                acc[r] = fmaf(hv.z, wz, acc[r]);
                acc[r] = fmaf(hv.w, ww, acc[r]);
            }
        }
        #pragma unroll
        for (int r = 0; r < 16; ++r) {
            out[(size_t)(n0 + grp * 16 + r) * FEATS + j] = fmaxf(acc[r], 0.0f);
        }
    }
}

// ---------------------------------------------------------------------------
// Fused dense (layer 2) + classifier: h2 tile lives one barrier in LDS
// (reuses `rows`), lin_w staged in LDS (stride 108). Deletes h write+read.
// ---------------------------------------------------------------------------
__global__ __launch_bounds__(256) void dense_cls_kernel(
        const float* __restrict__ in,      // neigh2 [N][100]
        const float* __restrict__ W,       // W2 [100][100]
        const float* __restrict__ b,       // b2 [100]
        const float* __restrict__ lin_w,   // [50][100]
        const float* __restrict__ lin_b,   // [50]
        float* __restrict__ out) {         // [N][50]
    __shared__ float rows[32][FEATS];
    __shared__ float lws[NCLS][108];
    const int tid = threadIdx.x;
    const int n0 = blockIdx.x * 32;
    const int j = tid & 127;
    const int grp = tid >> 7;

    // Stage input rows + lin_w
    for (int i = tid; i < 32 * (FEATS / 4); i += 256) {
        int r = i / (FEATS / 4);
        int k4 = i - r * (FEATS / 4);
        float4 v = reinterpret_cast<const float4*>(in + (size_t)(n0 + r) * FEATS)[k4];
        *reinterpret_cast<float4*>(&rows[r][k4 * 4]) = v;
    }
    for (int i = tid; i < NCLS * FEATS; i += 256) {
        int r = i / FEATS;
        lws[r][i - r * FEATS] = lin_w[i];
    }

    float w[FEATS];
    float bias = 0.0f;
    if (j < FEATS) {
        bias = b[j];
        #pragma unroll
        for (int k4 = 0; k4 < FEATS / 4; ++k4) {
            float4 v = reinterpret_cast<const float4*>(W + (size_t)j * FEATS)[k4];
            w[4 * k4 + 0] = v.x;
            w[4 * k4 + 1] = v.y;
            w[4 * k4 + 2] = v.z;
            w[4 * k4 + 3] = v.w;
        }
    }
    __syncthreads();

    // Dense phase
    float acc[16];
    if (j < FEATS) {
        #pragma unroll
        for (int r = 0; r < 16; ++r) acc[r] = bias;
        #pragma unroll
        for (int k4 = 0; k4 < FEATS / 4; ++k4) {
            const float wx = w[4 * k4 + 0];
            const float wy = w[4 * k4 + 1];
            const float wz = w[4 * k4 + 2];
            const float ww = w[4 * k4 + 3];
            #pragma unroll
            for (int r = 0; r < 16; ++r) {
                float4 hv = *reinterpret_cast<const float4*>(&rows[grp * 16 + r][4 * k4]);
                acc[r] = fmaf(hv.x, wx, acc[r]);
                acc[r] = fmaf(hv.y, wy, acc[r]);
                acc[r] = fmaf(hv.z, wz, acc[r]);
                acc[r] = fmaf(hv.w, ww, acc[r]);
            }
        }
    }
    __syncthreads();   // rows fully consumed
    if (j < FEATS) {
        #pragma unroll
        for (int r = 0; r < 16; ++r) {
            rows[grp * 16 + r][j] = fmaxf(acc[r], 0.0f);   // h2 tile into rows
        }
    }
    __syncthreads();   // h2 ready

    // Classifier phase: wave w handles rows 8w..8w+7; lane c < 50
    const int c = tid & 63;
    const int rg = tid >> 6;
    if (c < NCLS) {
        float cacc[8];
        const float cb = lin_b[c];
        #pragma unroll
        for (int r = 0; r < 8; ++r) cacc[r] = cb;
        #pragma unroll
        for (int k4 = 0; k4 < FEATS / 4; ++k4) {
            float4 lw4 = *reinterpret_cast<const float4*>(&lws[c][4 * k4]);
            #pragma unroll
            for (int r = 0; r < 8; ++r) {
                float4 hv = *reinterpret_cast<const float4*>(&rows[rg * 8 + r][4 * k4]);
                cacc[r] = fmaf(hv.x, lw4.x, cacc[r]);
                cacc[r] = fmaf(hv.y, lw4.y, cacc[r]);
                cacc[r] = fmaf(hv.z, lw4.z, cacc[r]);
                cacc[r] = fmaf(hv.w, lw4.w, cacc[r]);
            }
        }
        #pragma unroll
        for (int r = 0; r < 8; ++r) {
            out[(size_t)(n0 + rg * 8 + r) * NCLS + c] = cacc[r];
        }
    }
}

// ---------------------------------------------------------------------------
extern "C" void kernel_launch(void* const* d_in, const int* in_sizes, int n_in,
                              void* d_out, int out_size, void* d_ws, size_t ws_size,
                              hipStream_t stream) {
    const float* features = (const float*)d_in[0];
    const int*   node_ids = (const int*)d_in[1];
    const int*   src      = (const int*)d_in[2];
    const int*   dst      = (const int*)d_in[3];
    const float* ew       = (const float*)d_in[4];
    const float* alpha    = (const float*)d_in[5];
    const float* W1       = (const float*)d_in[6];
    const float* b1       = (const float*)d_in[7];
    const float* W2       = (const float*)d_in[8];
    const float* b2       = (const float*)d_in[9];
    const float* lin_w    = (const float*)d_in[10];
    const float* lin_b    = (const float*)d_in[11];
    float* out = (float*)d_out;

    char* ws = (char*)d_ws;
    size_t off = 0;
    auto alloc = [&](size_t bytes) {
        void* p = ws + off;
        off += (bytes + 255) & ~(size_t)255;
        return p;
    };
    int*  deg    = (int*)alloc((size_t)N_NODES_C * 4);
    int*  bsum   = (int*)alloc((size_t)SCAN_NBLK * 4);
    int*  rp     = (int*)alloc((size_t)(N_NODES_C + 1) * 4);
    int*  cursor = (int*)alloc((size_t)(N_NODES_C + 1) * 4);
    int2* csr    = (int2*)alloc((size_t)N_EDGES_C * 8);
    float* neigh = (float*)alloc((size_t)N_NODES_C * FEATS * 4);
    float* h     = (float*)alloc((size_t)N_NODES_C * FEATS * 4);
    (void)ws_size;

    // --- CSR build ---
    hipMemsetAsync(deg, 0, (size_t)N_NODES_C * 4, stream);
    deg_count_kernel<<<(N_EDGES_C + 255) / 256, 256, 0, stream>>>(dst, deg);
    scan1_kernel<<<SCAN_NBLK, SCAN_BLK, 0, stream>>>(deg, bsum);
    scan2_kernel<<<1, 128, 0, stream>>>(bsum);
    scan3_kernel<<<SCAN_NBLK, SCAN_BLK, 0, stream>>>(deg, bsum, rp, cursor);
    csr_fill_kernel<<<(N_EDGES_C + 255) / 256, 256, 0, stream>>>(
        node_ids, src, dst, ew, alpha, cursor, csr);

    // --- Layer 1 ---
    aggregate_kernel<<<(N_NODES_C * 32) / 256, 256, 0, stream>>>(features, rp, csr, neigh);
    dense32_kernel<<<N_NODES_C / 32, 256, 0, stream>>>(neigh, W1, b1, h);

    // --- Layer 2 + classifier (dense+cls fused; gather stays separate) ---
    aggregate_kernel<<<(N_NODES_C * 32) / 256, 256, 0, stream>>>(h, rp, csr, neigh);
    dense_cls_kernel<<<N_NODES_C / 32, 256, 0, stream>>>(neigh, W2, b2, lin_w, lin_b, out);
}

// Round 6
// 364.845 us; speedup vs baseline: 1.3200x; 1.3200x over previous
//
#include <hip/hip_runtime.h>

#define N_NODES_C 100000
#define N_EDGES_C 800000
#define FEATS 100
#define NCLS 50
#define GENE 20000
#define SCAN_BLK 1024
#define SCAN_NBLK ((N_NODES_C + SCAN_BLK - 1) / SCAN_BLK)   // 98

// ---------------------------------------------------------------------------
// Degree count (int atomics)
// ---------------------------------------------------------------------------
__global__ void deg_count_kernel(const int* __restrict__ dst,
                                 int* __restrict__ deg) {
    int e = blockIdx.x * blockDim.x + threadIdx.x;
    if (e >= N_EDGES_C) return;
    atomicAdd(&deg[dst[e]], 1);
}

// ---------------------------------------------------------------------------
// 3-kernel exclusive scan over deg[100000] -> row_ptr[100001]
// ---------------------------------------------------------------------------
__global__ __launch_bounds__(1024) void scan1_kernel(int* __restrict__ deg,
                                                     int* __restrict__ bsum) {
    __shared__ int wsum[16];
    const int i = blockIdx.x * SCAN_BLK + threadIdx.x;
    const int lane = threadIdx.x & 63;
    const int wid = threadIdx.x >> 6;
    int v = (i < N_NODES_C) ? deg[i] : 0;
    #pragma unroll
    for (int d = 1; d < 64; d <<= 1) {
        int t = __shfl_up(v, d);
        if (lane >= d) v += t;
    }
    if (lane == 63) wsum[wid] = v;
    __syncthreads();
    if (wid == 0) {
        int s = (lane < 16) ? wsum[lane] : 0;
        #pragma unroll
        for (int d = 1; d < 16; d <<= 1) {
            int t = __shfl_up(s, d);
            if (lane >= d) s += t;
        }
        if (lane < 16) wsum[lane] = s;
    }
    __syncthreads();
    if (wid > 0) v += wsum[wid - 1];
    if (i < N_NODES_C) deg[i] = v;
    if (threadIdx.x == SCAN_BLK - 1) bsum[blockIdx.x] = v;
}

__global__ void scan2_kernel(int* __restrict__ bsum) {
    __shared__ int tmp[SCAN_NBLK];
    if (threadIdx.x < SCAN_NBLK) tmp[threadIdx.x] = bsum[threadIdx.x];
    __syncthreads();
    if (threadIdx.x == 0) {
        int off = 0;
        for (int j = 0; j < SCAN_NBLK; ++j) { int t = tmp[j]; tmp[j] = off; off += t; }
    }
    __syncthreads();
    if (threadIdx.x < SCAN_NBLK) bsum[threadIdx.x] = tmp[threadIdx.x];
}

__global__ __launch_bounds__(1024) void scan3_kernel(const int* __restrict__ incl,
                                                     const int* __restrict__ boff,
                                                     int* __restrict__ rp,
                                                     int* __restrict__ cursor) {
    int i = blockIdx.x * SCAN_BLK + threadIdx.x;
    if (i >= N_NODES_C) return;
    int v = incl[i] + boff[blockIdx.x];
    rp[i + 1] = v;
    cursor[i + 1] = v;
    if (i == 0) { rp[0] = 0; cursor[0] = 0; }
}

// ---------------------------------------------------------------------------
// CSR fill: per edge compute scale inline, append (src, scale) to dst bucket
// ---------------------------------------------------------------------------
__global__ void csr_fill_kernel(const int* __restrict__ node_ids,
                                const int* __restrict__ src,
                                const int* __restrict__ dst,
                                const float* __restrict__ ew,
                                const float* __restrict__ alpha,
                                int* __restrict__ cursor,
                                int2* __restrict__ csr) {
    int e = blockIdx.x * blockDim.x + threadIdx.x;
    if (e >= N_EDGES_C) return;
    int s = src[e];
    int d = dst[e];
    int sid = node_ids[s];
    int did = node_ids[d];
    int idx = GENE + 1;                        // cell-cell
    if (sid >= 0 && did < 0) idx = sid;        // gene -> cell
    else if (did >= 0 && sid < 0) idx = did;   // cell -> gene
    else if (sid >= 0 && did >= 0) idx = GENE; // gene -> gene
    float sc = alpha[idx] * ew[e];
    int pos = atomicAdd(&cursor[d], 1);
    csr[pos] = make_int2(s, __float_as_int(sc));
}

// ---------------------------------------------------------------------------
// Aggregation v4: 2 nodes per wave (32 lanes each, float4 x 25 slots),
// 8-deep clamped unroll -> 8 independent row loads in flight per half-wave.
// Zero-weight fmaf for the clamped tail (exact no-op, order-preserving).
// ---------------------------------------------------------------------------
__global__ __launch_bounds__(256) void aggregate_kernel(
        const float* __restrict__ hin,
        const int* __restrict__ rp,
        const int2* __restrict__ csr,
        float* __restrict__ neigh) {
    const int node = (blockIdx.x * 256 + threadIdx.x) >> 5;
    const int lane = threadIdx.x & 31;
    const int ll = (lane < FEATS / 4) ? lane : (FEATS / 4 - 1);  // clamp
    if (node >= N_NODES_C) return;
    const int beg = rp[node];
    const int end = rp[node + 1];
    float a0 = 0.0f, a1 = 0.0f, a2 = 0.0f, a3 = 0.0f;
    for (int k = beg; k < end; k += 8) {
        int kk[8];
        #pragma unroll
        for (int i = 0; i < 8; ++i) kk[i] = min(k + i, end - 1);
        int2 e0 = csr[kk[0]];
        int2 e1 = csr[kk[1]];
        int2 e2 = csr[kk[2]];
        int2 e3 = csr[kk[3]];
        int2 e4 = csr[kk[4]];
        int2 e5 = csr[kk[5]];
        int2 e6 = csr[kk[6]];
        int2 e7 = csr[kk[7]];
        float4 x0 = ((const float4*)(hin + (size_t)e0.x * FEATS))[ll];
        float4 x1 = ((const float4*)(hin + (size_t)e1.x * FEATS))[ll];
        float4 x2 = ((const float4*)(hin + (size_t)e2.x * FEATS))[ll];
        float4 x3 = ((const float4*)(hin + (size_t)e3.x * FEATS))[ll];
        float4 x4 = ((const float4*)(hin + (size_t)e4.x * FEATS))[ll];
        float4 x5 = ((const float4*)(hin + (size_t)e5.x * FEATS))[ll];
        float4 x6 = ((const float4*)(hin + (size_t)e6.x * FEATS))[ll];
        float4 x7 = ((const float4*)(hin + (size_t)e7.x * FEATS))[ll];
        float w0 = __int_as_float(e0.y);
        float w1 = (k + 1 < end) ? __int_as_float(e1.y) : 0.0f;
        float w2 = (k + 2 < end) ? __int_as_float(e2.y) : 0.0f;
        float w3 = (k + 3 < end) ? __int_as_float(e3.y) : 0.0f;
        float w4 = (k + 4 < end) ? __int_as_float(e4.y) : 0.0f;
        float w5 = (k + 5 < end) ? __int_as_float(e5.y) : 0.0f;
        float w6 = (k + 6 < end) ? __int_as_float(e6.y) : 0.0f;
        float w7 = (k + 7 < end) ? __int_as_float(e7.y) : 0.0f;
        a0 = fmaf(x0.x, w0, a0); a1 = fmaf(x0.y, w0, a1);
        a2 = fmaf(x0.z, w0, a2); a3 = fmaf(x0.w, w0, a3);
        a0 = fmaf(x1.x, w1, a0); a1 = fmaf(x1.y, w1, a1);
        a2 = fmaf(x1.z, w1, a2); a3 = fmaf(x1.w, w1, a3);
        a0 = fmaf(x2.x, w2, a0); a1 = fmaf(x2.y, w2, a1);
        a2 = fmaf(x2.z, w2, a2); a3 = fmaf(x2.w, w2, a3);
        a0 = fmaf(x3.x, w3, a0); a1 = fmaf(x3.y, w3, a1);
        a2 = fmaf(x3.z, w3, a2); a3 = fmaf(x3.w, w3, a3);
        a0 = fmaf(x4.x, w4, a0); a1 = fmaf(x4.y, w4, a1);
        a2 = fmaf(x4.z, w4, a2); a3 = fmaf(x4.w, w4, a3);
        a0 = fmaf(x5.x, w5, a0); a1 = fmaf(x5.y, w5, a1);
        a2 = fmaf(x5.z, w5, a2); a3 = fmaf(x5.w, w5, a3);
        a0 = fmaf(x6.x, w6, a0); a1 = fmaf(x6.y, w6, a1);
        a2 = fmaf(x6.z, w6, a2); a3 = fmaf(x6.w, w6, a3);
        a0 = fmaf(x7.x, w7, a0); a1 = fmaf(x7.y, w7, a1);
        a2 = fmaf(x7.z, w7, a2); a3 = fmaf(x7.w, w7, a3);
    }
    const float invd = (end > beg) ? 1.0f / (float)(end - beg) : 0.0f;
    if (lane < FEATS / 4) {
        ((float4*)(neigh + (size_t)node * FEATS))[lane] =
            make_float4(a0 * invd, a1 * invd, a2 * invd, a3 * invd);
    }
}

// ---------------------------------------------------------------------------
// Dense: one 32-row tile per block (grid = N/32 = 3125). 256 threads.
// NOUT=100: 2 groups x 16 rows, j = tid&127 (<100 active)
// NOUT=50 : 4 groups x  8 rows, j = tid&63  (<50 active)
// W row in VGPRs; rows staged float4; broadcast LDS reads.  (round-4 proven)
// ---------------------------------------------------------------------------
template <int NOUT, bool RELU>
__global__ __launch_bounds__(256) void dense32_kernel(
        const float* __restrict__ in,
        const float* __restrict__ W,
        const float* __restrict__ b,
        float* __restrict__ out) {
    constexpr int RPT   = (NOUT == 100) ? 16 : 8;   // rows per thread
    constexpr int JMASK = (NOUT == 100) ? 127 : 63;
    constexpr int GS    = (NOUT == 100) ? 7 : 6;

    __shared__ float rows[32][FEATS];
    const int tid = threadIdx.x;
    const int n0 = blockIdx.x * 32;
    const int j = tid & JMASK;
    const int grp = tid >> GS;

    for (int i = tid; i < 32 * (FEATS / 4); i += 256) {
        int r = i / (FEATS / 4);
        int k4 = i - r * (FEATS / 4);
        float4 v = reinterpret_cast<const float4*>(in + (size_t)(n0 + r) * FEATS)[k4];
        *reinterpret_cast<float4*>(&rows[r][k4 * 4]) = v;
    }

    float w[FEATS];
    float bias = 0.0f;
    if (j < NOUT) {
        bias = b[j];
        #pragma unroll
        for (int k4 = 0; k4 < FEATS / 4; ++k4) {
            float4 v = reinterpret_cast<const float4*>(W + (size_t)j * FEATS)[k4];
            w[4 * k4 + 0] = v.x;
            w[4 * k4 + 1] = v.y;
            w[4 * k4 + 2] = v.z;
            w[4 * k4 + 3] = v.w;
        }
    }
    __syncthreads();

    if (j < NOUT) {
        float acc[RPT];
        #pragma unroll
        for (int r = 0; r < RPT; ++r) acc[r] = bias;
        #pragma unroll
        for (int k4 = 0; k4 < FEATS / 4; ++k4) {
            const float wx = w[4 * k4 + 0];
            const float wy = w[4 * k4 + 1];
            const float wz = w[4 * k4 + 2];
            const float ww = w[4 * k4 + 3];
            #pragma unroll
            for (int r = 0; r < RPT; ++r) {
                float4 hv = *reinterpret_cast<const float4*>(&rows[grp * RPT + r][4 * k4]);
                acc[r] = fmaf(hv.x, wx, acc[r]);
                acc[r] = fmaf(hv.y, wy, acc[r]);
                acc[r] = fmaf(hv.z, wz, acc[r]);
                acc[r] = fmaf(hv.w, ww, acc[r]);
            }
        }
        #pragma unroll
        for (int r = 0; r < RPT; ++r) {
            float v = RELU ? fmaxf(acc[r], 0.0f) : acc[r];
            out[(size_t)(n0 + grp * RPT + r) * NOUT + j] = v;
        }
    }
}

// ---------------------------------------------------------------------------
extern "C" void kernel_launch(void* const* d_in, const int* in_sizes, int n_in,
                              void* d_out, int out_size, void* d_ws, size_t ws_size,
                              hipStream_t stream) {
    const float* features = (const float*)d_in[0];
    const int*   node_ids = (const int*)d_in[1];
    const int*   src      = (const int*)d_in[2];
    const int*   dst      = (const int*)d_in[3];
    const float* ew       = (const float*)d_in[4];
    const float* alpha    = (const float*)d_in[5];
    const float* W1       = (const float*)d_in[6];
    const float* b1       = (const float*)d_in[7];
    const float* W2       = (const float*)d_in[8];
    const float* b2       = (const float*)d_in[9];
    const float* lin_w    = (const float*)d_in[10];
    const float* lin_b    = (const float*)d_in[11];
    float* out = (float*)d_out;

    char* ws = (char*)d_ws;
    size_t off = 0;
    auto alloc = [&](size_t bytes) {
        void* p = ws + off;
        off += (bytes + 255) & ~(size_t)255;
        return p;
    };
    int*  deg    = (int*)alloc((size_t)N_NODES_C * 4);
    int*  bsum   = (int*)alloc((size_t)SCAN_NBLK * 4);
    int*  rp     = (int*)alloc((size_t)(N_NODES_C + 1) * 4);
    int*  cursor = (int*)alloc((size_t)(N_NODES_C + 1) * 4);
    int2* csr    = (int2*)alloc((size_t)N_EDGES_C * 8);
    float* neigh = (float*)alloc((size_t)N_NODES_C * FEATS * 4);
    float* h     = (float*)alloc((size_t)N_NODES_C * FEATS * 4);
    (void)ws_size;

    // --- CSR build ---
    hipMemsetAsync(deg, 0, (size_t)N_NODES_C * 4, stream);
    deg_count_kernel<<<(N_EDGES_C + 255) / 256, 256, 0, stream>>>(dst, deg);
    scan1_kernel<<<SCAN_NBLK, SCAN_BLK, 0, stream>>>(deg, bsum);
    scan2_kernel<<<1, 128, 0, stream>>>(bsum);
    scan3_kernel<<<SCAN_NBLK, SCAN_BLK, 0, stream>>>(deg, bsum, rp, cursor);
    csr_fill_kernel<<<(N_EDGES_C + 255) / 256, 256, 0, stream>>>(
        node_ids, src, dst, ew, alpha, cursor, csr);

    // --- Layer 1 ---
    aggregate_kernel<<<(N_NODES_C * 32) / 256, 256, 0, stream>>>(features, rp, csr, neigh);
    dense32_kernel<FEATS, true><<<N_NODES_C / 32, 256, 0, stream>>>(neigh, W1, b1, h);

    // --- Layer 2 ---
    aggregate_kernel<<<(N_NODES_C * 32) / 256, 256, 0, stream>>>(h, rp, csr, neigh);
    dense32_kernel<FEATS, true><<<N_NODES_C / 32, 256, 0, stream>>>(neigh, W2, b2, h);

    // --- Classifier ---
    dense32_kernel<NCLS, false><<<N_NODES_C / 32, 256, 0, stream>>>(h, lin_w, lin_b, out);
}